// Round 2
// baseline (415.719 us; speedup 1.0000x reference)
//
#include <hip/hip_runtime.h>
#include <hip/hip_bf16.h>
#include <cstdint>

#define NEGV (-10000.0f)

typedef short bf16x8 __attribute__((ext_vector_type(8)));
typedef short bf16x4 __attribute__((ext_vector_type(4)));
typedef float f32x4 __attribute__((ext_vector_type(4)));

__device__ __forceinline__ short f2bf(float f) {
  union { float f; uint32_t u; } v; v.f = f;
  uint32_t u = v.u + 0x7fffu + ((v.u >> 16) & 1u);
  return (short)(u >> 16);
}
__device__ __forceinline__ float b2f(short s) {
  union { uint32_t u; float f; } v; v.u = ((uint32_t)(uint16_t)s) << 16;
  return v.f;
}
// pack 2 floats -> 2 bf16 in a u32 (compiler fuses to v_cvt_pk_bf16_f32)
__device__ __forceinline__ uint32_t pk2(float lo, float hi) {
  union { __hip_bfloat162 h2; uint32_t u; } cv;
  cv.h2.x = __float2bfloat16(lo);
  cv.h2.y = __float2bfloat16(hi);
  return cv.u;
}

// ---------------- P1: weight combine + bf16 casts ----------------
__global__ void prep_weights(const float* __restrict__ W1, const float* __restrict__ W2,
                             short* __restrict__ Wk, short* __restrict__ Wd,
                             short* __restrict__ W2b) {
  int idx = blockIdx.x * 256 + threadIdx.x;
  if (idx < 32768) {
    int h = idx >> 7, d = idx & 127;
    Wk[idx] = f2bf(W1[h * 512 + 128 + d] - W1[h * 512 + 256 + d]);
  } else if (idx < 65536) {
    int i = idx - 32768;
    int h = i >> 7, d = i & 127;
    Wd[i] = f2bf(W1[h * 512 + 384 + d]);
  } else {
    int i = idx - 65536;
    W2b[i] = f2bf(W2[i]);
  }
}

// ---------------- P2: U[b][h] = b1[h] + sum_d (W1[h][d]+W1[h][256+d]) * q[b][d] ----
__global__ void prep_u(const float* __restrict__ query, const float* __restrict__ W1,
                       const float* __restrict__ b1, float* __restrict__ U) {
  __shared__ float q8[8][128];
  int tid = threadIdx.x;
  int b0 = blockIdx.x * 8;
  for (int i = tid; i < 1024; i += 256)
    q8[i >> 7][i & 127] = query[(size_t)(b0 + (i >> 7)) * 128 + (i & 127)];
  __syncthreads();
  int h = tid;
  const float4* w0 = (const float4*)(W1 + (size_t)h * 512);
  const float4* w1 = (const float4*)(W1 + (size_t)h * 512 + 256);
  float acc[8];
  float bb = b1[h];
#pragma unroll
  for (int i = 0; i < 8; ++i) acc[i] = bb;
  for (int d4 = 0; d4 < 32; ++d4) {
    float4 wa = w0[d4], wb = w1[d4];
    float wv0 = wa.x + wb.x, wv1 = wa.y + wb.y, wv2 = wa.z + wb.z, wv3 = wa.w + wb.w;
#pragma unroll
    for (int i = 0; i < 8; ++i) {
      float4 qv = ((const float4*)q8[i])[d4];
      acc[i] += wv0 * qv.x + wv1 * qv.y + wv2 * qv.z + wv3 * qv.w;
    }
  }
#pragma unroll
  for (int i = 0; i < 8; ++i) U[(size_t)(b0 + i) * 256 + h] = acc[i];
}

// ---------------- main: one block (8 waves) per batch row ----------------
__global__ __launch_bounds__(512, 4) void din_main(
    const float* __restrict__ query, const float* __restrict__ keys,
    const int* __restrict__ mask,
    const float* __restrict__ b2p, const float* __restrict__ a1p,
    const float* __restrict__ a2p, const float* __restrict__ W3,
    const float* __restrict__ b3p,
    const float* __restrict__ U, const short* __restrict__ Wk,
    const short* __restrict__ Wd, const short* __restrict__ W2b,
    float* __restrict__ out) {
  __shared__ short Kp[2][64 * 128];   // phase key tile, bf16, XOR-swizzled (16B slots)
  __shared__ short H1[64 * 256];      // h1 phase tile [l][h], bf16, XOR-swizzled
  __shared__ float scores[208];
  __shared__ float wl[208];
  __shared__ float Ul[256];
  __shared__ float b2l[128];
  __shared__ float w3l[128];
  __shared__ float red[16];
  __shared__ float opart[16 * 128];

  const int tid = threadIdx.x;
  const int b = blockIdx.x;
  const int lane = tid & 63, wid = tid >> 6;  // 8 waves
  const int lr = lane & 15, lg = lane >> 4;

  const float a1 = a1p[0], a2 = a2p[0], b3 = b3p[0];

  if (tid < 256) Ul[tid] = U[(size_t)b * 256 + tid];
  if (tid < 128) { b2l[tid] = b2p[tid]; w3l[tid] = W3[tid]; }
  if (tid < 208) scores[tid] = b3;

  // ---- persistent fragments ----
  // GEMM1 A-operand: M_b[h][d] = Wk + Wd .* q ; wave owns 32 h-cols (2 nt)
  bf16x8 mf[2][4];
  {
    const float* qrow = query + (size_t)b * 128;
#pragma unroll
    for (int nt = 0; nt < 2; ++nt) {
      int h = wid * 32 + nt * 16 + lr;
#pragma unroll
      for (int ks = 0; ks < 4; ++ks) {
        int d0 = ks * 32 + lg * 8;
        bf16x8 wk = *(const bf16x8*)(Wk + h * 128 + d0);
        bf16x8 wd = *(const bf16x8*)(Wd + h * 128 + d0);
        float4 q0 = *(const float4*)(qrow + d0);
        float4 q1 = *(const float4*)(qrow + d0 + 4);
        float qv[8] = {q0.x, q0.y, q0.z, q0.w, q1.x, q1.y, q1.z, q1.w};
        float mv[8];
#pragma unroll
        for (int j = 0; j < 8; ++j) mv[j] = b2f(wk[j]) + b2f(wd[j]) * qv[j];
        union { bf16x8 v; uint32_t u[4]; } mm;
#pragma unroll
        for (int j = 0; j < 4; ++j) mm.u[j] = pk2(mv[2 * j], mv[2 * j + 1]);
        mf[nt][ks] = mm.v;
      }
    }
  }
  // GEMM2 A-operand: W2[g][h]; wave owns 16 g-cols
  bf16x8 w2f[8];
  {
    int g = wid * 16 + lr;
#pragma unroll
    for (int ks = 0; ks < 8; ++ks)
      w2f[ks] = *(const bf16x8*)(W2b + g * 256 + ks * 32 + lg * 8);
  }

  const int srow = tid >> 3, sc = (tid & 7) * 16;
  // ---- prologue: stage phase 0 (rows 0..63, all valid) ----
  {
    const float4* kp4 = (const float4*)(keys + ((size_t)b * 200 + srow) * 128 + sc);
    float4 s0 = kp4[0], s1 = kp4[1], s2 = kp4[2], s3 = kp4[3];
    union { bf16x8 v; uint32_t u[4]; } w0, w1;
    w0.u[0] = pk2(s0.x, s0.y); w0.u[1] = pk2(s0.z, s0.w);
    w0.u[2] = pk2(s1.x, s1.y); w0.u[3] = pk2(s1.z, s1.w);
    w1.u[0] = pk2(s2.x, s2.y); w1.u[1] = pk2(s2.z, s2.w);
    w1.u[2] = pk2(s3.x, s3.y); w1.u[3] = pk2(s3.z, s3.w);
    int sw = (srow & 7) << 3;
    *(bf16x8*)(&Kp[0][srow * 128 + (sc ^ sw)]) = w0.v;
    *(bf16x8*)(&Kp[0][srow * 128 + ((sc + 8) ^ sw)]) = w1.v;
  }
  __syncthreads();

  // ---- 4 phases of 64 rows (last: 16) ----
  for (int p = 0; p < 4; ++p) {
    const int buf = p & 1;
    const int nsub = (p < 3) ? 4 : 1;

    // issue next-phase global loads early (latency hides under GEMM1)
    float4 st0, st1, st2, st3;
    bool svalid = false;
    if (p < 3) {
      int nrow = (p + 1 < 3) ? 64 : 16;
      svalid = srow < nrow;
      int sl = (p + 1) * 64 + srow;
      st0 = st1 = st2 = st3 = make_float4(0.f, 0.f, 0.f, 0.f);
      if (svalid && sl < 200) {
        const float4* kp4 = (const float4*)(keys + ((size_t)b * 200 + sl) * 128 + sc);
        st0 = kp4[0]; st1 = kp4[1]; st2 = kp4[2]; st3 = kp4[3];
      }
    }

    // GEMM1: D[h][l] = M_b · K^T  (swapped operands)
    for (int sub = 0; sub < nsub; ++sub) {
      const int l = sub * 16 + lr;
      const int sw = (lr & 7) << 3;
      bf16x8 kf[4];
#pragma unroll
      for (int ks = 0; ks < 4; ++ks)
        kf[ks] = *(const bf16x8*)(&Kp[buf][l * 128 + ((ks * 32 + lg * 8) ^ sw)]);
      f32x4 acc[2];
#pragma unroll
      for (int nt = 0; nt < 2; ++nt)
#pragma unroll
        for (int r = 0; r < 4; ++r) acc[nt][r] = Ul[wid * 32 + nt * 16 + lg * 4 + r];
#pragma unroll
      for (int ks = 0; ks < 4; ++ks)
#pragma unroll
        for (int nt = 0; nt < 2; ++nt)
          acc[nt] = __builtin_amdgcn_mfma_f32_16x16x32_bf16(mf[nt][ks], kf[ks], acc[nt], 0, 0, 0);
      // epilogue: PReLU(a1) -> H1[l][h] packed ds_write_b64
#pragma unroll
      for (int nt = 0; nt < 2; ++nt) {
        float v0 = acc[nt][0], v1 = acc[nt][1], v2 = acc[nt][2], v3 = acc[nt][3];
        v0 = (v0 >= 0.f) ? v0 : a1 * v0;
        v1 = (v1 >= 0.f) ? v1 : a1 * v1;
        v2 = (v2 >= 0.f) ? v2 : a1 * v2;
        v3 = (v3 >= 0.f) ? v3 : a1 * v3;
        union { bf16x4 v; uint32_t u[2]; } hh;
        hh.u[0] = pk2(v0, v1); hh.u[1] = pk2(v2, v3);
        int h0 = wid * 32 + nt * 16 + lg * 4;
        *(bf16x4*)(&H1[l * 256 + (h0 ^ sw)]) = hh.v;
      }
    }

    // write next-phase Kp (loads completed by now; hidden under GEMM1)
    if (svalid) {
      union { bf16x8 v; uint32_t u[4]; } w0, w1;
      w0.u[0] = pk2(st0.x, st0.y); w0.u[1] = pk2(st0.z, st0.w);
      w0.u[2] = pk2(st1.x, st1.y); w0.u[3] = pk2(st1.z, st1.w);
      w1.u[0] = pk2(st2.x, st2.y); w1.u[1] = pk2(st2.z, st2.w);
      w1.u[2] = pk2(st3.x, st3.y); w1.u[3] = pk2(st3.z, st3.w);
      int sw2 = (srow & 7) << 3;
      *(bf16x8*)(&Kp[buf ^ 1][srow * 128 + (sc ^ sw2)]) = w0.v;
      *(bf16x8*)(&Kp[buf ^ 1][srow * 128 + ((sc + 8) ^ sw2)]) = w1.v;
    }
    __syncthreads();

    // GEMM2: D[g][l] = W2 · H1^T  (swapped operands)
    for (int sub = 0; sub < nsub; ++sub) {
      const int hrow = sub * 16 + lr;
      const int sw = (lr & 7) << 3;
      f32x4 acc2;
#pragma unroll
      for (int r = 0; r < 4; ++r) acc2[r] = b2l[wid * 16 + lg * 4 + r];
#pragma unroll
      for (int ks = 0; ks < 8; ++ks) {
        bf16x8 hf = *(const bf16x8*)(&H1[hrow * 256 + ((ks * 32 + lg * 8) ^ sw)]);
        acc2 = __builtin_amdgcn_mfma_f32_16x16x32_bf16(w2f[ks], hf, acc2, 0, 0, 0);
      }
      float s = 0.f;
#pragma unroll
      for (int r = 0; r < 4; ++r) {
        float v = acc2[r];
        v = (v >= 0.f) ? v : a2 * v;
        s += v * w3l[wid * 16 + lg * 4 + r];
      }
      s += __shfl_xor(s, 16);
      s += __shfl_xor(s, 32);
      if (lg == 0) atomicAdd(&scores[p * 64 + sub * 16 + lr], s);
    }
    __syncthreads();
  }

  // ---- masked softmax over L=200 (fp32) ----
  float val = NEGV;
  int mk = 0;
  if (tid < 200) {
    mk = mask[(size_t)b * 200 + tid];
    val = mk ? scores[tid] : NEGV;
  }
  float m = val;
#pragma unroll
  for (int off = 1; off < 64; off <<= 1) m = fmaxf(m, __shfl_xor(m, off));
  if (lane == 0) red[wid] = m;
  __syncthreads();
  float smax = red[0];
#pragma unroll
  for (int i = 1; i < 8; ++i) smax = fmaxf(smax, red[i]);
  float pex = (tid < 200 && mk) ? __expf(val - smax) : 0.f;
  float s = pex;
#pragma unroll
  for (int off = 1; off < 64; off <<= 1) s += __shfl_xor(s, off);
  if (lane == 0) red[8 + wid] = s;
  __syncthreads();
  float ssum = 0.f;
#pragma unroll
  for (int i = 0; i < 8; ++i) ssum += red[8 + i];
  float winv = (ssum > 0.f) ? 1.f / ssum : 0.f;
  if (tid < 208) wl[tid] = (tid < 200) ? pex * winv : 0.f;
  __syncthreads();

  // ---- weighted sum: out[b][d] = sum_l w[l]*keys[b][l][d], fp32 from global ----
  {
    const int d4 = (tid & 31) << 2;  // 0..124
    const int slice = tid >> 5;      // 0..15
    float ax = 0.f, ay = 0.f, az = 0.f, aw = 0.f;
    for (int l = slice; l < 200; l += 16) {
      float wv = wl[l];
      float4 kv = *(const float4*)(keys + ((size_t)b * 200 + l) * 128 + d4);
      ax += wv * kv.x; ay += wv * kv.y; az += wv * kv.z; aw += wv * kv.w;
    }
    float4 r4 = make_float4(ax, ay, az, aw);
    *(float4*)(&opart[slice * 128 + d4]) = r4;
  }
  __syncthreads();
  if (tid < 128) {
    float acc = 0.f;
#pragma unroll
    for (int i = 0; i < 16; ++i) acc += opart[i * 128 + tid];
    out[(size_t)b * 128 + tid] = acc;
  }
}

extern "C" void kernel_launch(void* const* d_in, const int* in_sizes, int n_in,
                              void* d_out, int out_size, void* d_ws, size_t ws_size,
                              hipStream_t stream) {
  const float* query = (const float*)d_in[0];
  const float* keys  = (const float*)d_in[1];
  const int*   maskp = (const int*)d_in[2];
  const float* W1    = (const float*)d_in[3];
  const float* b1    = (const float*)d_in[4];
  const float* a1    = (const float*)d_in[5];
  const float* W2    = (const float*)d_in[6];
  const float* b2    = (const float*)d_in[7];
  const float* a2    = (const float*)d_in[8];
  const float* W3    = (const float*)d_in[9];
  const float* b3    = (const float*)d_in[10];
  float* out = (float*)d_out;

  float* U   = (float*)d_ws;                         // 2 MiB
  short* Wk  = (short*)((char*)d_ws + 2097152);      // 64 KiB
  short* Wd  = Wk + 32768;                           // 64 KiB
  short* W2b = Wd + 32768;                           // 64 KiB

  prep_weights<<<384, 256, 0, stream>>>(W1, W2, Wk, Wd, W2b);
  prep_u<<<256, 256, 0, stream>>>(query, W1, b1, U);
  din_main<<<2048, 512, 0, stream>>>(query, keys, maskp, b2, a1, a2, W3, b3,
                                     U, Wk, Wd, W2b, out);
}

// Round 3
// 209.299 us; speedup vs baseline: 1.9862x; 1.9862x over previous
//
#include <hip/hip_runtime.h>
#include <hip/hip_bf16.h>
#include <cstdint>

#define NEGV (-10000.0f)

typedef short bf16x8 __attribute__((ext_vector_type(8)));
typedef short bf16x4 __attribute__((ext_vector_type(4)));
typedef float f32x4 __attribute__((ext_vector_type(4)));

__device__ __forceinline__ short f2bf(float f) {
  union { float f; uint32_t u; } v; v.f = f;
  uint32_t u = v.u + 0x7fffu + ((v.u >> 16) & 1u);
  return (short)(u >> 16);
}
__device__ __forceinline__ float b2f(short s) {
  union { uint32_t u; float f; } v; v.u = ((uint32_t)(uint16_t)s) << 16;
  return v.f;
}
// pack 2 floats -> 2 bf16 in a u32 (v_cvt_pk_bf16_f32)
__device__ __forceinline__ uint32_t pk2(float lo, float hi) {
  union { __hip_bfloat162 h2; uint32_t u; } cv;
  cv.h2.x = __float2bfloat16(lo);
  cv.h2.y = __float2bfloat16(hi);
  return cv.u;
}

// ---------------- P1: weight combine + bf16 casts ----------------
__global__ void prep_weights(const float* __restrict__ W1, const float* __restrict__ W2,
                             short* __restrict__ Wk, short* __restrict__ Wd,
                             short* __restrict__ W2b) {
  int idx = blockIdx.x * 256 + threadIdx.x;
  if (idx < 32768) {
    int h = idx >> 7, d = idx & 127;
    Wk[idx] = f2bf(W1[h * 512 + 128 + d] - W1[h * 512 + 256 + d]);
  } else if (idx < 65536) {
    int i = idx - 32768;
    int h = i >> 7, d = i & 127;
    Wd[i] = f2bf(W1[h * 512 + 384 + d]);
  } else {
    int i = idx - 65536;
    W2b[i] = f2bf(W2[i]);
  }
}

// ---------------- P2: U[b][h] = b1[h] + sum_d (W1[h][d]+W1[h][256+d]) * q[b][d] ----
__global__ void prep_u(const float* __restrict__ query, const float* __restrict__ W1,
                       const float* __restrict__ b1, float* __restrict__ U) {
  __shared__ float q8[8][128];
  int tid = threadIdx.x;
  int b0 = blockIdx.x * 8;
  for (int i = tid; i < 1024; i += 256)
    q8[i >> 7][i & 127] = query[(size_t)(b0 + (i >> 7)) * 128 + (i & 127)];
  __syncthreads();
  int h = tid;
  const float4* w0 = (const float4*)(W1 + (size_t)h * 512);
  const float4* w1 = (const float4*)(W1 + (size_t)h * 512 + 256);
  float acc[8];
  float bb = b1[h];
#pragma unroll
  for (int i = 0; i < 8; ++i) acc[i] = bb;
  for (int d4 = 0; d4 < 32; ++d4) {
    float4 wa = w0[d4], wb = w1[d4];
    float wv0 = wa.x + wb.x, wv1 = wa.y + wb.y, wv2 = wa.z + wb.z, wv3 = wa.w + wb.w;
#pragma unroll
    for (int i = 0; i < 8; ++i) {
      float4 qv = ((const float4*)q8[i])[d4];
      acc[i] += wv0 * qv.x + wv1 * qv.y + wv2 * qv.z + wv3 * qv.w;
    }
  }
#pragma unroll
  for (int i = 0; i < 8; ++i) U[(size_t)(b0 + i) * 256 + h] = acc[i];
}

// ---------------- main: one block (8 waves) per batch row ----------------
// __launch_bounds__ 2nd arg behaves as min BLOCKS per CU (R2 post-mortem:
// (512,4) capped VGPR at 64 -> 380MB spill writes). (512,2) -> cap 128 VGPR,
// matching the LDS-limited 2 blocks/CU.
__global__ __launch_bounds__(512, 2) void din_main(
    const float* __restrict__ query, const float* __restrict__ keys,
    const int* __restrict__ mask,
    const float* __restrict__ b2p, const float* __restrict__ a1p,
    const float* __restrict__ a2p, const float* __restrict__ W3,
    const float* __restrict__ b3p,
    const float* __restrict__ U, const short* __restrict__ Wk,
    const short* __restrict__ Wd, const short* __restrict__ W2b,
    float* __restrict__ out) {
  __shared__ short Kp[2][64 * 128];   // phase key tile, bf16, XOR-swizzled (16B slots)
  __shared__ short H1[64 * 256];      // h1 phase tile [l][h], bf16, XOR-swizzled
  __shared__ float scores[208];
  __shared__ float wl[208];
  __shared__ float Ul[256];
  __shared__ float b2l[128];
  __shared__ float w3l[128];
  __shared__ float red[16];
  __shared__ float opart[16 * 128];

  const int tid = threadIdx.x;
  const int b = blockIdx.x;
  const int lane = tid & 63, wid = tid >> 6;  // 8 waves
  const int lr = lane & 15, lg = lane >> 4;

  const float a1 = a1p[0], a2 = a2p[0], b3 = b3p[0];

  if (tid < 256) Ul[tid] = U[(size_t)b * 256 + tid];
  if (tid < 128) { b2l[tid] = b2p[tid]; w3l[tid] = W3[tid]; }
  if (tid < 208) scores[tid] = b3;

  // ---- persistent fragments ----
  // GEMM1 A-operand: M_b[h][d] = Wk + Wd .* q ; wave owns 32 h-cols (2 nt)
  bf16x8 mf[2][4];
  {
    const float* qrow = query + (size_t)b * 128;
#pragma unroll
    for (int nt = 0; nt < 2; ++nt) {
      int h = wid * 32 + nt * 16 + lr;
#pragma unroll
      for (int ks = 0; ks < 4; ++ks) {
        int d0 = ks * 32 + lg * 8;
        bf16x8 wk = *(const bf16x8*)(Wk + h * 128 + d0);
        bf16x8 wd = *(const bf16x8*)(Wd + h * 128 + d0);
        float4 q0 = *(const float4*)(qrow + d0);
        float4 q1 = *(const float4*)(qrow + d0 + 4);
        float qv[8] = {q0.x, q0.y, q0.z, q0.w, q1.x, q1.y, q1.z, q1.w};
        float mv[8];
#pragma unroll
        for (int j = 0; j < 8; ++j) mv[j] = b2f(wk[j]) + b2f(wd[j]) * qv[j];
        union { bf16x8 v; uint32_t u[4]; } mm;
#pragma unroll
        for (int j = 0; j < 4; ++j) mm.u[j] = pk2(mv[2 * j], mv[2 * j + 1]);
        mf[nt][ks] = mm.v;
      }
    }
  }
  // GEMM2 A-operand: W2[g][h]; wave owns 16 g-cols
  bf16x8 w2f[8];
  {
    int g = wid * 16 + lr;
#pragma unroll
    for (int ks = 0; ks < 8; ++ks)
      w2f[ks] = *(const bf16x8*)(W2b + g * 256 + ks * 32 + lg * 8);
  }

  const int srow = tid >> 3, sc = (tid & 7) * 16;
  // ---- prologue: stage phase 0 (rows 0..63, all valid) ----
  {
    const float4* kp4 = (const float4*)(keys + ((size_t)b * 200 + srow) * 128 + sc);
    float4 s0 = kp4[0], s1 = kp4[1], s2 = kp4[2], s3 = kp4[3];
    union { bf16x8 v; uint32_t u[4]; } w0, w1;
    w0.u[0] = pk2(s0.x, s0.y); w0.u[1] = pk2(s0.z, s0.w);
    w0.u[2] = pk2(s1.x, s1.y); w0.u[3] = pk2(s1.z, s1.w);
    w1.u[0] = pk2(s2.x, s2.y); w1.u[1] = pk2(s2.z, s2.w);
    w1.u[2] = pk2(s3.x, s3.y); w1.u[3] = pk2(s3.z, s3.w);
    int sw = (srow & 7) << 3;
    *(bf16x8*)(&Kp[0][srow * 128 + (sc ^ sw)]) = w0.v;
    *(bf16x8*)(&Kp[0][srow * 128 + ((sc + 8) ^ sw)]) = w1.v;
  }
  __syncthreads();

  // ---- 4 phases of 64 rows (last: 16) ----
  for (int p = 0; p < 4; ++p) {
    const int buf = p & 1;
    const int nsub = (p < 3) ? 4 : 1;

    // issue next-phase global loads early (latency hides under GEMM1)
    float4 st0, st1, st2, st3;
    bool svalid = false;
    if (p < 3) {
      int nrow = (p + 1 < 3) ? 64 : 16;
      svalid = srow < nrow;
      int sl = (p + 1) * 64 + srow;
      st0 = st1 = st2 = st3 = make_float4(0.f, 0.f, 0.f, 0.f);
      if (svalid && sl < 200) {
        const float4* kp4 = (const float4*)(keys + ((size_t)b * 200 + sl) * 128 + sc);
        st0 = kp4[0]; st1 = kp4[1]; st2 = kp4[2]; st3 = kp4[3];
      }
    }

    // GEMM1: D[h][l] = M_b · K^T  (swapped operands)
    for (int sub = 0; sub < nsub; ++sub) {
      const int l = sub * 16 + lr;
      const int sw = (lr & 7) << 3;
      bf16x8 kf[4];
#pragma unroll
      for (int ks = 0; ks < 4; ++ks)
        kf[ks] = *(const bf16x8*)(&Kp[buf][l * 128 + ((ks * 32 + lg * 8) ^ sw)]);
      f32x4 acc[2];
#pragma unroll
      for (int nt = 0; nt < 2; ++nt)
#pragma unroll
        for (int r = 0; r < 4; ++r) acc[nt][r] = Ul[wid * 32 + nt * 16 + lg * 4 + r];
#pragma unroll
      for (int ks = 0; ks < 4; ++ks)
#pragma unroll
        for (int nt = 0; nt < 2; ++nt)
          acc[nt] = __builtin_amdgcn_mfma_f32_16x16x32_bf16(mf[nt][ks], kf[ks], acc[nt], 0, 0, 0);
      // epilogue: PReLU(a1) -> H1[l][h] packed ds_write_b64
#pragma unroll
      for (int nt = 0; nt < 2; ++nt) {
        float v0 = acc[nt][0], v1 = acc[nt][1], v2 = acc[nt][2], v3 = acc[nt][3];
        v0 = (v0 >= 0.f) ? v0 : a1 * v0;
        v1 = (v1 >= 0.f) ? v1 : a1 * v1;
        v2 = (v2 >= 0.f) ? v2 : a1 * v2;
        v3 = (v3 >= 0.f) ? v3 : a1 * v3;
        union { bf16x4 v; uint32_t u[2]; } hh;
        hh.u[0] = pk2(v0, v1); hh.u[1] = pk2(v2, v3);
        int h0 = wid * 32 + nt * 16 + lg * 4;
        *(bf16x4*)(&H1[l * 256 + (h0 ^ sw)]) = hh.v;
      }
    }

    // write next-phase Kp (loads completed by now; hidden under GEMM1)
    if (svalid) {
      union { bf16x8 v; uint32_t u[4]; } w0, w1;
      w0.u[0] = pk2(st0.x, st0.y); w0.u[1] = pk2(st0.z, st0.w);
      w0.u[2] = pk2(st1.x, st1.y); w0.u[3] = pk2(st1.z, st1.w);
      w1.u[0] = pk2(st2.x, st2.y); w1.u[1] = pk2(st2.z, st2.w);
      w1.u[2] = pk2(st3.x, st3.y); w1.u[3] = pk2(st3.z, st3.w);
      int sw2 = (srow & 7) << 3;
      *(bf16x8*)(&Kp[buf ^ 1][srow * 128 + (sc ^ sw2)]) = w0.v;
      *(bf16x8*)(&Kp[buf ^ 1][srow * 128 + ((sc + 8) ^ sw2)]) = w1.v;
    }
    __syncthreads();

    // GEMM2: D[g][l] = W2 · H1^T  (swapped operands)
    for (int sub = 0; sub < nsub; ++sub) {
      const int hrow = sub * 16 + lr;
      const int sw = (lr & 7) << 3;
      f32x4 acc2;
#pragma unroll
      for (int r = 0; r < 4; ++r) acc2[r] = b2l[wid * 16 + lg * 4 + r];
#pragma unroll
      for (int ks = 0; ks < 8; ++ks) {
        bf16x8 hf = *(const bf16x8*)(&H1[hrow * 256 + ((ks * 32 + lg * 8) ^ sw)]);
        acc2 = __builtin_amdgcn_mfma_f32_16x16x32_bf16(w2f[ks], hf, acc2, 0, 0, 0);
      }
      float s = 0.f;
#pragma unroll
      for (int r = 0; r < 4; ++r) {
        float v = acc2[r];
        v = (v >= 0.f) ? v : a2 * v;
        s += v * w3l[wid * 16 + lg * 4 + r];
      }
      s += __shfl_xor(s, 16);
      s += __shfl_xor(s, 32);
      if (lg == 0) atomicAdd(&scores[p * 64 + sub * 16 + lr], s);
    }
    __syncthreads();
  }

  // ---- masked softmax over L=200 (fp32) ----
  float val = NEGV;
  int mk = 0;
  if (tid < 200) {
    mk = mask[(size_t)b * 200 + tid];
    val = mk ? scores[tid] : NEGV;
  }
  float m = val;
#pragma unroll
  for (int off = 1; off < 64; off <<= 1) m = fmaxf(m, __shfl_xor(m, off));
  if (lane == 0) red[wid] = m;
  __syncthreads();
  float smax = red[0];
#pragma unroll
  for (int i = 1; i < 8; ++i) smax = fmaxf(smax, red[i]);
  float pex = (tid < 200 && mk) ? __expf(val - smax) : 0.f;
  float s = pex;
#pragma unroll
  for (int off = 1; off < 64; off <<= 1) s += __shfl_xor(s, off);
  if (lane == 0) red[8 + wid] = s;
  __syncthreads();
  float ssum = 0.f;
#pragma unroll
  for (int i = 0; i < 8; ++i) ssum += red[8 + i];
  float winv = (ssum > 0.f) ? 1.f / ssum : 0.f;
  if (tid < 208) wl[tid] = (tid < 200) ? pex * winv : 0.f;
  __syncthreads();

  // ---- weighted sum: out[b][d] = sum_l w[l]*keys[b][l][d], fp32 from global ----
  {
    const int d4 = (tid & 31) << 2;  // 0..124
    const int slice = tid >> 5;      // 0..15
    float ax = 0.f, ay = 0.f, az = 0.f, aw = 0.f;
    for (int l = slice; l < 200; l += 16) {
      float wv = wl[l];
      float4 kv = *(const float4*)(keys + ((size_t)b * 200 + l) * 128 + d4);
      ax += wv * kv.x; ay += wv * kv.y; az += wv * kv.z; aw += wv * kv.w;
    }
    float4 r4 = make_float4(ax, ay, az, aw);
    *(float4*)(&opart[slice * 128 + d4]) = r4;
  }
  __syncthreads();
  if (tid < 128) {
    float acc = 0.f;
#pragma unroll
    for (int i = 0; i < 16; ++i) acc += opart[i * 128 + tid];
    out[(size_t)b * 128 + tid] = acc;
  }
}

extern "C" void kernel_launch(void* const* d_in, const int* in_sizes, int n_in,
                              void* d_out, int out_size, void* d_ws, size_t ws_size,
                              hipStream_t stream) {
  const float* query = (const float*)d_in[0];
  const float* keys  = (const float*)d_in[1];
  const int*   maskp = (const int*)d_in[2];
  const float* W1    = (const float*)d_in[3];
  const float* b1    = (const float*)d_in[4];
  const float* a1    = (const float*)d_in[5];
  const float* W2    = (const float*)d_in[6];
  const float* b2    = (const float*)d_in[7];
  const float* a2    = (const float*)d_in[8];
  const float* W3    = (const float*)d_in[9];
  const float* b3    = (const float*)d_in[10];
  float* out = (float*)d_out;

  float* U   = (float*)d_ws;                         // 2 MiB
  short* Wk  = (short*)((char*)d_ws + 2097152);      // 64 KiB
  short* Wd  = Wk + 32768;                           // 64 KiB
  short* W2b = Wd + 32768;                           // 64 KiB

  prep_weights<<<384, 256, 0, stream>>>(W1, W2, Wk, Wd, W2b);
  prep_u<<<256, 256, 0, stream>>>(query, W1, b1, U);
  din_main<<<2048, 512, 0, stream>>>(query, keys, maskp, b2, a1, a2, W3, b3,
                                     U, Wk, Wd, W2b, out);
}